// Round 1
// 908.189 us; speedup vs baseline: 1.0448x; 1.0448x over previous
//
#include <hip/hip_runtime.h>
#include <math.h>

#define NBOND 7
#define NLAY 8
#define NTYPE 6
#define NNODES 16384   // B*N = 128*128
#define PX 136         // LDS pitch in halves (272 B, 16B-aligned; 68 dw % 32 = 4 -> conflict-clean)

typedef _Float16 half8 __attribute__((ext_vector_type(8)));
typedef _Float16 half4 __attribute__((ext_vector_type(4)));
typedef float floatx16 __attribute__((ext_vector_type(16)));

__device__ __forceinline__ float sig_(float x) { return 1.0f / (1.0f + __expf(-x)); }
// D-layout for 32x32 MFMA: col = lane&31, row = (reg&3) + 8*(reg>>2) + 4*(lane>>5)
__device__ __forceinline__ int drow_(int reg, int hi) { return (reg & 3) + 8 * (reg >> 2) + 4 * hi; }

__device__ __forceinline__ _Float16 hi_(float v) { return (_Float16)v; }
__device__ __forceinline__ _Float16 lo_(float v) { return (_Float16)(v - (float)(_Float16)v); }

// ---------------------------------------------------------------- setup
__global__ void setup_kernel(const float* __restrict__ h, float* __restrict__ hT,
                             int* __restrict__ counts, int* __restrict__ bucket)
{
    int gid = blockIdx.x * 256 + threadIdx.x;
    int node = gid >> 7, d = gid & 127;
    hT[gid] = (d < 75) ? h[node * 75 + d] : 0.0f;
    if (gid < NNODES) {
        float a = h[gid * 75];
        int tt = 5;
        if      (a == 6.0f) tt = 0;
        else if (a == 7.0f) tt = 1;
        else if (a == 8.0f) tt = 2;
        else if (a == 9.0f) tt = 3;
        else if (a == 0.0f) tt = 4;
        int slot = atomicAdd(&counts[tt], 1);
        bucket[tt * NNODES + slot] = gid;
    }
}

// ---------------------------------------------------------------- weight packing (fp32 -> split fp16 hi/lo planes)
// msgW: [(kb*8+l)][c 0..15][plane hi/lo][e 0..127][j 0..7]  (j along input dim d)
__global__ void pack_msg_kernel(const float* __restrict__ msgW, _Float16* __restrict__ Wp)
{
    int idx = blockIdx.x * 256 + threadIdx.x;
    if (idx >= NBOND * NLAY * 16 * 128) return;
    int e  = idx & 127;
    int c  = (idx >> 7) & 15;
    int kl = idx >> 11;
    const float* src = msgW + ((size_t)kl * 128 + e) * 128 + c * 8;
    float4 u = *(const float4*)src;
    float4 v = *(const float4*)(src + 4);
    float av[8] = {u.x, u.y, u.z, u.w, v.x, v.y, v.z, v.w};
    half8 hh, ll;
    #pragma unroll
    for (int j = 0; j < 8; ++j) { hh[j] = hi_(av[j]); ll[j] = lo_(av[j]); }
    _Float16* dst = Wp + ((size_t)kl * 16 + c) * 2048;
    *(half8*)(dst + e * 8)        = hh;
    *(half8*)(dst + 1024 + e * 8) = ll;
}

// GRU: [(vt*2+mat)][c 0..15][plane hi/lo][col 0..383][j 0..7]
__global__ void pack_gru_kernel(const float* __restrict__ Wih, const float* __restrict__ Whh,
                                _Float16* __restrict__ Wp)
{
    int idx = blockIdx.x * 256 + threadIdx.x;
    if (idx >= 2 * NTYPE * 2 * 16 * 384) return;
    int col = idx % 384;
    int c   = (idx / 384) & 15;
    int vm  = idx / 6144;       // (vt*2 + mat), vt = v*6+tt
    int mat = vm & 1;
    int vt  = vm >> 1;
    const float* src = (mat ? Whh : Wih) + ((size_t)vt * 384 + col) * 128 + c * 8;
    float4 u = *(const float4*)src;
    float4 v = *(const float4*)(src + 4);
    float av[8] = {u.x, u.y, u.z, u.w, v.x, v.y, v.z, v.w};
    half8 hh, ll;
    #pragma unroll
    for (int j = 0; j < 8; ++j) { hh[j] = hi_(av[j]); ll[j] = lo_(av[j]); }
    _Float16* dst = Wp + (size_t)vm * 98304 + (size_t)c * 6144;
    *(half8*)(dst + col * 8)        = hh;
    *(half8*)(dst + 3072 + col * 8) = ll;
}

// ---------------------------------------------------------------- MLP + aggregation (split-fp16 MFMA)
// One block per (kb, b): 128 nodes resident in LDS (hi/lo planes) through 8 layers.
// Wave w owns row-tile w (rows w*32..+31) and ALL 4 col-tiles. KEY: each wave's
// layer output rows == its own A rows, so layers 0..6 need NO barriers — waves
// free-run through the MLP chain, hiding L2 weight-load latency against each
// other. Barriers only: after initial stage, and around the final transposed store.
__global__ __launch_bounds__(256) void mlp_agg_mfma(
    const float* __restrict__ hin, const _Float16* __restrict__ Wp,
    const float* __restrict__ gmat, float* __restrict__ m_non, float* __restrict__ m_uni)
{
    __shared__ _Float16 Xhi[128 * PX];
    __shared__ _Float16 Xlo[128 * PX];

    const int t = threadIdx.x;
    const int kb = blockIdx.x, b = blockIdx.y;
    const int wave = t >> 6, lane = t & 63, lo = lane & 31, hi = lane >> 5;
    const int row = wave * 32 + lo;   // A-operand row for this lane

    // stage layer-0 activations (fp32 -> hi/lo fp16)
    for (int q = t; q < 128 * 32; q += 256) {
        int r = q >> 5, c4 = q & 31;
        float4 v = *(const float4*)(hin + ((size_t)(b * 128 + r)) * 128 + c4 * 4);
        half4 hh, ll;
        hh[0] = hi_(v.x); ll[0] = lo_(v.x);
        hh[1] = hi_(v.y); ll[1] = lo_(v.y);
        hh[2] = hi_(v.z); ll[2] = lo_(v.z);
        hh[3] = hi_(v.w); ll[3] = lo_(v.w);
        *(half4*)(Xhi + r * PX + c4 * 4) = hh;
        *(half4*)(Xlo + r * PX + c4 * 4) = ll;
    }
    __syncthreads();

    floatx16 acc[4];

    #pragma unroll 1
    for (int l = 0; l < NLAY; ++l) {
        #pragma unroll
        for (int ct = 0; ct < 4; ++ct) acc[ct] = (floatx16)0.0f;
        const _Float16* wb = Wp + ((size_t)(kb * NLAY + l) * 16) * 2048;

        #pragma unroll 2
        for (int kk = 0; kk < 8; ++kk) {
            half8 a_h = *(const half8*)(Xhi + row * PX + kk * 16 + hi * 8);
            half8 a_l = *(const half8*)(Xlo + row * PX + kk * 16 + hi * 8);
            const _Float16* bp = wb + (size_t)(kk * 2 + hi) * 2048;
            #pragma unroll
            for (int ct = 0; ct < 4; ++ct) {
                half8 b_h = *(const half8*)(bp + (ct * 32 + lo) * 8);
                half8 b_l = *(const half8*)(bp + 1024 + (ct * 32 + lo) * 8);
                acc[ct] = __builtin_amdgcn_mfma_f32_32x32x16_f16(a_h, b_h, acc[ct], 0, 0, 0);
                acc[ct] = __builtin_amdgcn_mfma_f32_32x32x16_f16(a_h, b_l, acc[ct], 0, 0, 0);
                acc[ct] = __builtin_amdgcn_mfma_f32_32x32x16_f16(a_l, b_h, acc[ct], 0, 0, 0);
            }
        }

        if (l < NLAY - 1) {
            // wave-local writeback (rows wave*32..+31 only): no barrier needed.
            // In-wave RAW through LDS is ordered by lgkmcnt (DS pipe is in-order).
            #pragma unroll
            for (int ct = 0; ct < 4; ++ct)
                #pragma unroll
                for (int reg = 0; reg < 16; ++reg) {
                    int n = wave * 32 + drow_(reg, hi);
                    float vv = fmaxf(acc[ct][reg], 0.0f);
                    Xhi[n * PX + ct * 32 + lo] = hi_(vv);
                    Xlo[n * PX + ct * 32 + lo] = lo_(vv);
                }
        } else {
            // final layer: transposed store Xt[e][m] crosses wave regions -> barrier pair
            __syncthreads();   // all waves' layer-7 A reads done
            #pragma unroll
            for (int ct = 0; ct < 4; ++ct)
                #pragma unroll
                for (int s = 0; s < 4; ++s) {
                    int e = ct * 32 + lo, m0 = wave * 32 + 8 * s + 4 * hi;
                    half4 hh, ll;
                    #pragma unroll
                    for (int j = 0; j < 4; ++j) {
                        float vv = acc[ct][4 * s + j];
                        hh[j] = hi_(vv); ll[j] = lo_(vv);
                    }
                    *(half4*)(Xhi + e * PX + m0) = hh;
                    *(half4*)(Xlo + e * PX + m0) = ll;
                }
            __syncthreads();   // Xt visible to all waves for aggregation
        }
    }

    // ---- aggregation: m[n][d] = sum_m g[b,kb,n,m]*xb[m][d];  A = g (inline split), B = Xt ----
    #pragma unroll
    for (int ct = 0; ct < 4; ++ct) acc[ct] = (floatx16)0.0f;
    const float* grow = gmat + (size_t)(b * NBOND + kb) * 16384;

    #pragma unroll 2
    for (int kk = 0; kk < 8; ++kk) {
        const float* gp = grow + (size_t)row * 128 + kk * 16 + hi * 8;
        float4 u = *(const float4*)gp, v2 = *(const float4*)(gp + 4);
        float av[8] = {u.x, u.y, u.z, u.w, v2.x, v2.y, v2.z, v2.w};
        half8 a_h, a_l;
        #pragma unroll
        for (int j = 0; j < 8; ++j) { a_h[j] = hi_(av[j]); a_l[j] = lo_(av[j]); }
        #pragma unroll
        for (int ct = 0; ct < 4; ++ct) {
            half8 b_h = *(const half8*)(Xhi + (ct * 32 + lo) * PX + kk * 16 + hi * 8);
            half8 b_l = *(const half8*)(Xlo + (ct * 32 + lo) * PX + kk * 16 + hi * 8);
            acc[ct] = __builtin_amdgcn_mfma_f32_32x32x16_f16(a_h, b_h, acc[ct], 0, 0, 0);
            acc[ct] = __builtin_amdgcn_mfma_f32_32x32x16_f16(a_h, b_l, acc[ct], 0, 0, 0);
            acc[ct] = __builtin_amdgcn_mfma_f32_32x32x16_f16(a_l, b_h, acc[ct], 0, 0, 0);
        }
    }

    if (kb == NBOND - 1) {
        #pragma unroll
        for (int ct = 0; ct < 4; ++ct)
            #pragma unroll
            for (int reg = 0; reg < 16; ++reg) {
                int n = wave * 32 + drow_(reg, hi);
                m_uni[((size_t)(b * 128 + n)) * 128 + ct * 32 + lo] = acc[ct][reg];
            }
    } else {
        #pragma unroll
        for (int ct = 0; ct < 4; ++ct)
            #pragma unroll
            for (int reg = 0; reg < 16; ++reg) {
                int n = wave * 32 + drow_(reg, hi);
                atomicAdd(m_non + ((size_t)(b * 128 + n)) * 128 + ct * 32 + lo, acc[ct][reg]);
            }
    }
}

// ---------------------------------------------------------------- grouped GRU (split-fp16 MFMA)
// Grid split 4x over z = (v*2 + rtile): each block owns 32 gathered nodes of one
// type for ONE GRU variant. LDS 35 KB (vs 68) -> up to 4 blocks/CU; M staged once.
// The two variants' outputs combine via atomicAdd into a zeroed hout buffer
// (h ping-pongs between ws and d_out across passes).
__global__ __launch_bounds__(256, 3) void gru_mfma(
    const float* __restrict__ hin, float* __restrict__ hout,
    const float* __restrict__ m_non, const float* __restrict__ m_uni,
    const int* __restrict__ counts, const int* __restrict__ bucket,
    const _Float16* __restrict__ Wp, const float* __restrict__ bihp, const float* __restrict__ bhhp)
{
    __shared__ _Float16 Xh[32 * PX], Xl[32 * PX], Mh[32 * PX], Ml[32 * PX];
    __shared__ int bl[32];

    const int t = threadIdx.x, tt = blockIdx.y;
    const int v = blockIdx.z >> 1, rtile = blockIdx.z & 1;
    const int cnt  = counts[tt];
    const int base = blockIdx.x * 64 + rtile * 32;
    if (base >= cnt) return;
    const int nn = min(32, cnt - base);
    if (t < 32) bl[t] = (t < nn) ? bucket[tt * NNODES + base + t] : -1;
    __syncthreads();

    const float* msrc = v ? m_uni : m_non;

    // stage X and M (32 gathered rows, split fp16, zero-fill inactive)
    for (int q = t; q < 32 * 32; q += 256) {
        int r = q >> 5, c4 = q & 31;
        float4 xv = make_float4(0.f, 0.f, 0.f, 0.f);
        float4 mv = make_float4(0.f, 0.f, 0.f, 0.f);
        int node = bl[r];
        if (node >= 0) {
            xv = *(const float4*)(hin  + (size_t)node * 128 + c4 * 4);
            mv = *(const float4*)(msrc + (size_t)node * 128 + c4 * 4);
        }
        half4 hh, ll;
        hh[0] = hi_(xv.x); ll[0] = lo_(xv.x);
        hh[1] = hi_(xv.y); ll[1] = lo_(xv.y);
        hh[2] = hi_(xv.z); ll[2] = lo_(xv.z);
        hh[3] = hi_(xv.w); ll[3] = lo_(xv.w);
        *(half4*)(Xh + r * PX + c4 * 4) = hh;
        *(half4*)(Xl + r * PX + c4 * 4) = ll;
        hh[0] = hi_(mv.x); ll[0] = lo_(mv.x);
        hh[1] = hi_(mv.y); ll[1] = lo_(mv.y);
        hh[2] = hi_(mv.z); ll[2] = lo_(mv.z);
        hh[3] = hi_(mv.w); ll[3] = lo_(mv.w);
        *(half4*)(Mh + r * PX + c4 * 4) = hh;
        *(half4*)(Ml + r * PX + c4 * 4) = ll;
    }
    __syncthreads();

    const int wave = t >> 6, lane = t & 63, lo = lane & 31, hi = lane >> 5;
    const int d = wave * 32 + lo;
    const int vt = v * NTYPE + tt;
    const _Float16* pih = Wp + (size_t)(vt * 2 + 0) * 98304;
    const _Float16* phh = Wp + (size_t)(vt * 2 + 1) * 98304;

    floatx16 ar = (floatx16)0.0f, az = (floatx16)0.0f;
    floatx16 ax = (floatx16)0.0f, ah = (floatx16)0.0f;

    #pragma unroll 2
    for (int kk = 0; kk < 8; ++kk) {
        int koff = kk * 16 + hi * 8;
        half8 xh = *(const half8*)(Xh + lo * PX + koff);
        half8 xl = *(const half8*)(Xl + lo * PX + koff);
        half8 mh = *(const half8*)(Mh + lo * PX + koff);
        half8 ml = *(const half8*)(Ml + lo * PX + koff);
        const _Float16* ci = pih + (size_t)(kk * 2 + hi) * 6144;
        const _Float16* ch = phh + (size_t)(kk * 2 + hi) * 6144;
        half8 birh = *(const half8*)(ci + (0   + d) * 8);
        half8 birl = *(const half8*)(ci + 3072 + (0   + d) * 8);
        half8 bizh = *(const half8*)(ci + (128 + d) * 8);
        half8 bizl = *(const half8*)(ci + 3072 + (128 + d) * 8);
        half8 binh = *(const half8*)(ci + (256 + d) * 8);
        half8 binl = *(const half8*)(ci + 3072 + (256 + d) * 8);
        half8 bhrh = *(const half8*)(ch + (0   + d) * 8);
        half8 bhrl = *(const half8*)(ch + 3072 + (0   + d) * 8);
        half8 bhzh = *(const half8*)(ch + (128 + d) * 8);
        half8 bhzl = *(const half8*)(ch + 3072 + (128 + d) * 8);
        half8 bhnh = *(const half8*)(ch + (256 + d) * 8);
        half8 bhnl = *(const half8*)(ch + 3072 + (256 + d) * 8);

        ar = __builtin_amdgcn_mfma_f32_32x32x16_f16(xh, birh, ar, 0, 0, 0);
        ar = __builtin_amdgcn_mfma_f32_32x32x16_f16(xh, birl, ar, 0, 0, 0);
        ar = __builtin_amdgcn_mfma_f32_32x32x16_f16(xl, birh, ar, 0, 0, 0);
        ar = __builtin_amdgcn_mfma_f32_32x32x16_f16(mh, bhrh, ar, 0, 0, 0);
        ar = __builtin_amdgcn_mfma_f32_32x32x16_f16(mh, bhrl, ar, 0, 0, 0);
        ar = __builtin_amdgcn_mfma_f32_32x32x16_f16(ml, bhrh, ar, 0, 0, 0);

        az = __builtin_amdgcn_mfma_f32_32x32x16_f16(xh, bizh, az, 0, 0, 0);
        az = __builtin_amdgcn_mfma_f32_32x32x16_f16(xh, bizl, az, 0, 0, 0);
        az = __builtin_amdgcn_mfma_f32_32x32x16_f16(xl, bizh, az, 0, 0, 0);
        az = __builtin_amdgcn_mfma_f32_32x32x16_f16(mh, bhzh, az, 0, 0, 0);
        az = __builtin_amdgcn_mfma_f32_32x32x16_f16(mh, bhzl, az, 0, 0, 0);
        az = __builtin_amdgcn_mfma_f32_32x32x16_f16(ml, bhzh, az, 0, 0, 0);

        ax = __builtin_amdgcn_mfma_f32_32x32x16_f16(xh, binh, ax, 0, 0, 0);
        ax = __builtin_amdgcn_mfma_f32_32x32x16_f16(xh, binl, ax, 0, 0, 0);
        ax = __builtin_amdgcn_mfma_f32_32x32x16_f16(xl, binh, ax, 0, 0, 0);
        ah = __builtin_amdgcn_mfma_f32_32x32x16_f16(mh, bhnh, ah, 0, 0, 0);
        ah = __builtin_amdgcn_mfma_f32_32x32x16_f16(mh, bhnl, ah, 0, 0, 0);
        ah = __builtin_amdgcn_mfma_f32_32x32x16_f16(ml, bhnh, ah, 0, 0, 0);
    }

    const float* bi = bihp + (size_t)vt * 384;
    const float* bh = bhhp + (size_t)vt * 384;
    float b_r  = bi[d] + bh[d];
    float b_z  = bi[128 + d] + bh[128 + d];
    float b_in = bi[256 + d];
    float b_hn = bh[256 + d];
    #pragma unroll
    for (int reg = 0; reg < 16; ++reg) {
        int n = drow_(reg, hi);
        int node = bl[n];
        if (node < 0) continue;
        float r  = sig_(ar[reg] + b_r);
        float z  = sig_(az[reg] + b_z);
        float nv = tanhf(ax[reg] + b_in + r * (ah[reg] + b_hn));
        float mv = msrc[(size_t)node * 128 + d];   // fp32 m for z*m
        atomicAdd(hout + (size_t)node * 128 + d, (1.0f - z) * nv + z * mv);
    }
}

// ---------------------------------------------------------------- launch
extern "C" void kernel_launch(void* const* d_in, const int* in_sizes, int n_in,
                              void* d_out, int out_size, void* d_ws, size_t ws_size,
                              hipStream_t stream) {
    const float* g    = (const float*)d_in[0];
    const float* h    = (const float*)d_in[1];
    const float* msgW = (const float*)d_in[2];
    const float* Wih  = (const float*)d_in[3];
    const float* Whh  = (const float*)d_in[4];
    const float* bih  = (const float*)d_in[5];
    const float* bhh  = (const float*)d_in[6];
    float* h1 = (float*)d_out;

    char* ws = (char*)d_ws;
    float* m_non = (float*)ws;                                   // 8 MB
    float* m_uni = m_non + (size_t)NNODES * 128;                 // 8 MB
    int* counts  = (int*)(ws + 2 * (size_t)NNODES * 128 * 4);
    int* bucket  = counts + 8;                                   // [6][16384]
    _Float16* WpM = (_Float16*)(bucket + NTYPE * NNODES);        // 1,835,008 halves (3.67 MB)
    _Float16* WpG = WpM + (size_t)NBOND * NLAY * 16 * 2048;      // 2,359,296 halves (4.72 MB)
    float* h0 = (float*)(WpG + (size_t)2 * NTYPE * 2 * 98304);   // 8 MB ping-pong h buffer

    (void)hipMemsetAsync(counts, 0, 8 * sizeof(int), stream);
    setup_kernel<<<NNODES * 128 / 256, 256, 0, stream>>>(h, h0, counts, bucket);
    pack_msg_kernel<<<(NBOND * NLAY * 16 * 128 + 255) / 256, 256, 0, stream>>>(msgW, WpM);
    pack_gru_kernel<<<(2 * NTYPE * 2 * 16 * 384 + 255) / 256, 256, 0, stream>>>(Wih, Whh, WpG);

    // h ping-pong: p0 h0->h1(d_out), p1 h1->h0, p2 h0->h1(d_out)
    const float* hin_p[3]  = {h0, h1, h0};
    float*       hout_p[3] = {h1, h0, h1};
    for (int pass = 0; pass < 3; ++pass) {
        (void)hipMemsetAsync(m_non, 0, (size_t)NNODES * 128 * 4, stream);
        (void)hipMemsetAsync(hout_p[pass], 0, (size_t)NNODES * 128 * 4, stream);
        mlp_agg_mfma<<<dim3(NBOND, 128), 256, 0, stream>>>(hin_p[pass], WpM, g, m_non, m_uni);
        gru_mfma<<<dim3(NNODES / 64, NTYPE, 4), 256, 0, stream>>>(hin_p[pass], hout_p[pass],
                                                                  m_non, m_uni, counts, bucket,
                                                                  WpG, bih, bhh);
    }
}

// Round 2
// 904.813 us; speedup vs baseline: 1.0487x; 1.0037x over previous
//
#include <hip/hip_runtime.h>
#include <math.h>

#define NBOND 7
#define NLAY 8
#define NTYPE 6
#define NNODES 16384   // B*N = 128*128
#define PX 136         // LDS pitch in halves (272 B, 16B-aligned; 68 dw % 32 = 4 -> conflict-clean)

typedef _Float16 half8 __attribute__((ext_vector_type(8)));
typedef _Float16 half4 __attribute__((ext_vector_type(4)));
typedef float floatx16 __attribute__((ext_vector_type(16)));

__device__ __forceinline__ float sig_(float x) { return 1.0f / (1.0f + __expf(-x)); }
// D-layout for 32x32 MFMA: col = lane&31, row = (reg&3) + 8*(reg>>2) + 4*(lane>>5)
__device__ __forceinline__ int drow_(int reg, int hi) { return (reg & 3) + 8 * (reg >> 2) + 4 * hi; }

__device__ __forceinline__ _Float16 hi_(float v) { return (_Float16)v; }
__device__ __forceinline__ _Float16 lo_(float v) { return (_Float16)(v - (float)(_Float16)v); }

// ---------------------------------------------------------------- setup
__global__ void setup_kernel(const float* __restrict__ h, float* __restrict__ hT,
                             int* __restrict__ counts, int* __restrict__ bucket)
{
    int gid = blockIdx.x * 256 + threadIdx.x;
    int node = gid >> 7, d = gid & 127;
    hT[gid] = (d < 75) ? h[node * 75 + d] : 0.0f;
    if (gid < NNODES) {
        float a = h[gid * 75];
        int tt = 5;
        if      (a == 6.0f) tt = 0;
        else if (a == 7.0f) tt = 1;
        else if (a == 8.0f) tt = 2;
        else if (a == 9.0f) tt = 3;
        else if (a == 0.0f) tt = 4;
        int slot = atomicAdd(&counts[tt], 1);
        bucket[tt * NNODES + slot] = gid;
    }
}

// ---------------------------------------------------------------- weight packing (fp32 -> split fp16 hi/lo planes)
// msgW: [(kb*8+l)][c 0..15][plane hi/lo][e 0..127][j 0..7]  (j along input dim d)
__global__ void pack_msg_kernel(const float* __restrict__ msgW, _Float16* __restrict__ Wp)
{
    int idx = blockIdx.x * 256 + threadIdx.x;
    if (idx >= NBOND * NLAY * 16 * 128) return;
    int e  = idx & 127;
    int c  = (idx >> 7) & 15;
    int kl = idx >> 11;
    const float* src = msgW + ((size_t)kl * 128 + e) * 128 + c * 8;
    float4 u = *(const float4*)src;
    float4 v = *(const float4*)(src + 4);
    float av[8] = {u.x, u.y, u.z, u.w, v.x, v.y, v.z, v.w};
    half8 hh, ll;
    #pragma unroll
    for (int j = 0; j < 8; ++j) { hh[j] = hi_(av[j]); ll[j] = lo_(av[j]); }
    _Float16* dst = Wp + ((size_t)kl * 16 + c) * 2048;
    *(half8*)(dst + e * 8)        = hh;
    *(half8*)(dst + 1024 + e * 8) = ll;
}

// GRU: [(vt*2+mat)][c 0..15][plane hi/lo][col 0..383][j 0..7]
__global__ void pack_gru_kernel(const float* __restrict__ Wih, const float* __restrict__ Whh,
                                _Float16* __restrict__ Wp)
{
    int idx = blockIdx.x * 256 + threadIdx.x;
    if (idx >= 2 * NTYPE * 2 * 16 * 384) return;
    int col = idx % 384;
    int c   = (idx / 384) & 15;
    int vm  = idx / 6144;       // (vt*2 + mat), vt = v*6+tt
    int mat = vm & 1;
    int vt  = vm >> 1;
    const float* src = (mat ? Whh : Wih) + ((size_t)vt * 384 + col) * 128 + c * 8;
    float4 u = *(const float4*)src;
    float4 v = *(const float4*)(src + 4);
    float av[8] = {u.x, u.y, u.z, u.w, v.x, v.y, v.z, v.w};
    half8 hh, ll;
    #pragma unroll
    for (int j = 0; j < 8; ++j) { hh[j] = hi_(av[j]); ll[j] = lo_(av[j]); }
    _Float16* dst = Wp + (size_t)vm * 98304 + (size_t)c * 6144;
    *(half8*)(dst + col * 8)        = hh;
    *(half8*)(dst + 3072 + col * 8) = ll;
}

// ---------------------------------------------------------------- MLP + aggregation (split-fp16 MFMA)
// One block per (kb, b): 128 nodes resident in LDS (hi/lo planes) through 8 layers.
// Wave w owns row-tile w and all 4 col-tiles; layers 0..6 are barrier-free
// (wave-local RAW through LDS, DS pipe in-order per wave).
// This version: 256-VGPR budget, explicit B-fragment double-buffer software-
// pipelined ACROSS layers (the VMEM queue never drains), and the aggregation
// g-tile preloaded into registers at the last kk of layer 7 (HBM latency hidden
// under layer-7 MFMAs + transpose + barrier; issued after the last B load so
// FIFO vmcnt waits on B never gate on the slower HBM g loads).
__global__ __launch_bounds__(256, 2) void mlp_agg_mfma(
    const float* __restrict__ hin, const _Float16* __restrict__ Wp,
    const float* __restrict__ gmat, float* __restrict__ m_non, float* __restrict__ m_uni)
{
    __shared__ _Float16 Xhi[128 * PX];
    __shared__ _Float16 Xlo[128 * PX];

    const int t = threadIdx.x;
    const int kb = blockIdx.x, b = blockIdx.y;
    const int wave = t >> 6, lane = t & 63, lo = lane & 31, hi = lane >> 5;
    const int row = wave * 32 + lo;   // A-operand row for this lane

    // stage layer-0 activations (fp32 -> hi/lo fp16)
    for (int q = t; q < 128 * 32; q += 256) {
        int r = q >> 5, c4 = q & 31;
        float4 v = *(const float4*)(hin + ((size_t)(b * 128 + r)) * 128 + c4 * 4);
        half4 hh, ll;
        hh[0] = hi_(v.x); ll[0] = lo_(v.x);
        hh[1] = hi_(v.y); ll[1] = lo_(v.y);
        hh[2] = hi_(v.z); ll[2] = lo_(v.z);
        hh[3] = hi_(v.w); ll[3] = lo_(v.w);
        *(half4*)(Xhi + r * PX + c4 * 4) = hh;
        *(half4*)(Xlo + r * PX + c4 * 4) = ll;
    }
    __syncthreads();

    floatx16 acc[4];
    half8 bcur_h[4], bcur_l[4];

    // prefetch (layer 0, kk 0)
    {
        const _Float16* bp = Wp + ((size_t)(kb * NLAY) * 16) * 2048 + (size_t)hi * 2048;
        #pragma unroll
        for (int ct = 0; ct < 4; ++ct) {
            bcur_h[ct] = *(const half8*)(bp + (ct * 32 + lo) * 8);
            bcur_l[ct] = *(const half8*)(bp + 1024 + (ct * 32 + lo) * 8);
        }
    }

    #pragma unroll 1
    for (int l = 0; l < NLAY - 1; ++l) {
        #pragma unroll
        for (int ct = 0; ct < 4; ++ct) acc[ct] = (floatx16)0.0f;
        const _Float16* wb = Wp + ((size_t)(kb * NLAY + l) * 16) * 2048;

        #pragma unroll
        for (int kk = 0; kk < 8; ++kk) {
            half8 bn_h[4], bn_l[4];
            // prefetch (l, kk+1), or (l+1, kk=0) at the layer tail
            const _Float16* bp = (kk < 7) ? (wb + (size_t)((kk + 1) * 2 + hi) * 2048)
                                          : (wb + (size_t)(16 * 2048) + (size_t)hi * 2048);
            #pragma unroll
            for (int ct = 0; ct < 4; ++ct) {
                bn_h[ct] = *(const half8*)(bp + (ct * 32 + lo) * 8);
                bn_l[ct] = *(const half8*)(bp + 1024 + (ct * 32 + lo) * 8);
            }
            half8 a_h = *(const half8*)(Xhi + row * PX + kk * 16 + hi * 8);
            half8 a_l = *(const half8*)(Xlo + row * PX + kk * 16 + hi * 8);
            #pragma unroll
            for (int ct = 0; ct < 4; ++ct) {
                acc[ct] = __builtin_amdgcn_mfma_f32_32x32x16_f16(a_h, bcur_h[ct], acc[ct], 0, 0, 0);
                acc[ct] = __builtin_amdgcn_mfma_f32_32x32x16_f16(a_h, bcur_l[ct], acc[ct], 0, 0, 0);
                acc[ct] = __builtin_amdgcn_mfma_f32_32x32x16_f16(a_l, bcur_h[ct], acc[ct], 0, 0, 0);
            }
            #pragma unroll
            for (int ct = 0; ct < 4; ++ct) { bcur_h[ct] = bn_h[ct]; bcur_l[ct] = bn_l[ct]; }
        }

        // ReLU writeback, wave-local rows only: no barrier needed
        #pragma unroll
        for (int ct = 0; ct < 4; ++ct)
            #pragma unroll
            for (int reg = 0; reg < 16; ++reg) {
                int n = wave * 32 + drow_(reg, hi);
                float vv = fmaxf(acc[ct][reg], 0.0f);
                Xhi[n * PX + ct * 32 + lo] = hi_(vv);
                Xlo[n * PX + ct * 32 + lo] = lo_(vv);
            }
    }

    // ---- layer 7 (peeled): bcur holds (7, kk=0) ----
    float4 greg[16];
    const float* grow = gmat + (size_t)(b * NBOND + kb) * 16384;
    {
        #pragma unroll
        for (int ct = 0; ct < 4; ++ct) acc[ct] = (floatx16)0.0f;
        const _Float16* wb = Wp + ((size_t)(kb * NLAY + 7) * 16) * 2048;

        #pragma unroll
        for (int kk = 0; kk < 8; ++kk) {
            half8 bn_h[4], bn_l[4];
            if (kk < 7) {
                const _Float16* bp = wb + (size_t)((kk + 1) * 2 + hi) * 2048;
                #pragma unroll
                for (int ct = 0; ct < 4; ++ct) {
                    bn_h[ct] = *(const half8*)(bp + (ct * 32 + lo) * 8);
                    bn_l[ct] = *(const half8*)(bp + 1024 + (ct * 32 + lo) * 8);
                }
            } else {
                // after the LAST B load: issue the HBM g-tile loads
                #pragma unroll
                for (int k2 = 0; k2 < 8; ++k2) {
                    const float* gp = grow + (size_t)row * 128 + k2 * 16 + hi * 8;
                    greg[k2 * 2]     = *(const float4*)gp;
                    greg[k2 * 2 + 1] = *(const float4*)(gp + 4);
                }
            }
            half8 a_h = *(const half8*)(Xhi + row * PX + kk * 16 + hi * 8);
            half8 a_l = *(const half8*)(Xlo + row * PX + kk * 16 + hi * 8);
            #pragma unroll
            for (int ct = 0; ct < 4; ++ct) {
                acc[ct] = __builtin_amdgcn_mfma_f32_32x32x16_f16(a_h, bcur_h[ct], acc[ct], 0, 0, 0);
                acc[ct] = __builtin_amdgcn_mfma_f32_32x32x16_f16(a_h, bcur_l[ct], acc[ct], 0, 0, 0);
                acc[ct] = __builtin_amdgcn_mfma_f32_32x32x16_f16(a_l, bcur_h[ct], acc[ct], 0, 0, 0);
            }
            if (kk < 7) {
                #pragma unroll
                for (int ct = 0; ct < 4; ++ct) { bcur_h[ct] = bn_h[ct]; bcur_l[ct] = bn_l[ct]; }
            }
        }
    }

    // transposed store Xt[e][m] (crosses wave regions -> barrier pair)
    __syncthreads();
    #pragma unroll
    for (int ct = 0; ct < 4; ++ct)
        #pragma unroll
        for (int s = 0; s < 4; ++s) {
            int e = ct * 32 + lo, m0 = wave * 32 + 8 * s + 4 * hi;
            half4 hh, ll;
            #pragma unroll
            for (int j = 0; j < 4; ++j) {
                float vv = acc[ct][4 * s + j];
                hh[j] = hi_(vv); ll[j] = lo_(vv);
            }
            *(half4*)(Xhi + e * PX + m0) = hh;
            *(half4*)(Xlo + e * PX + m0) = ll;
        }
    __syncthreads();

    // ---- aggregation: m[n][d] = sum_m g[b,kb,n,m]*xb[m][d]; A = greg (regs), B = Xt ----
    #pragma unroll
    for (int ct = 0; ct < 4; ++ct) acc[ct] = (floatx16)0.0f;

    #pragma unroll
    for (int kk = 0; kk < 8; ++kk) {
        float4 u = greg[kk * 2], v2 = greg[kk * 2 + 1];
        float av[8] = {u.x, u.y, u.z, u.w, v2.x, v2.y, v2.z, v2.w};
        half8 a_h, a_l;
        #pragma unroll
        for (int j = 0; j < 8; ++j) { a_h[j] = hi_(av[j]); a_l[j] = lo_(av[j]); }
        #pragma unroll
        for (int ct = 0; ct < 4; ++ct) {
            half8 b_h = *(const half8*)(Xhi + (ct * 32 + lo) * PX + kk * 16 + hi * 8);
            half8 b_l = *(const half8*)(Xlo + (ct * 32 + lo) * PX + kk * 16 + hi * 8);
            acc[ct] = __builtin_amdgcn_mfma_f32_32x32x16_f16(a_h, b_h, acc[ct], 0, 0, 0);
            acc[ct] = __builtin_amdgcn_mfma_f32_32x32x16_f16(a_h, b_l, acc[ct], 0, 0, 0);
            acc[ct] = __builtin_amdgcn_mfma_f32_32x32x16_f16(a_l, b_h, acc[ct], 0, 0, 0);
        }
    }

    if (kb == NBOND - 1) {
        #pragma unroll
        for (int ct = 0; ct < 4; ++ct)
            #pragma unroll
            for (int reg = 0; reg < 16; ++reg) {
                int n = wave * 32 + drow_(reg, hi);
                m_uni[((size_t)(b * 128 + n)) * 128 + ct * 32 + lo] = acc[ct][reg];
            }
    } else {
        #pragma unroll
        for (int ct = 0; ct < 4; ++ct)
            #pragma unroll
            for (int reg = 0; reg < 16; ++reg) {
                int n = wave * 32 + drow_(reg, hi);
                atomicAdd(m_non + ((size_t)(b * 128 + n)) * 128 + ct * 32 + lo, acc[ct][reg]);
            }
    }
}

// ---------------------------------------------------------------- grouped GRU (split-fp16 MFMA)
// Grid split 4x over z = (v*2 + rtile): each block owns 32 gathered nodes of one
// type for ONE GRU variant. LDS 35 KB -> up to 4 blocks/CU; M staged once.
// The two variants' outputs combine via atomicAdd into a zeroed hout buffer
// (h ping-pongs between ws and d_out across passes).
__global__ __launch_bounds__(256, 3) void gru_mfma(
    const float* __restrict__ hin, float* __restrict__ hout,
    const float* __restrict__ m_non, const float* __restrict__ m_uni,
    const int* __restrict__ counts, const int* __restrict__ bucket,
    const _Float16* __restrict__ Wp, const float* __restrict__ bihp, const float* __restrict__ bhhp)
{
    __shared__ _Float16 Xh[32 * PX], Xl[32 * PX], Mh[32 * PX], Ml[32 * PX];
    __shared__ int bl[32];

    const int t = threadIdx.x, tt = blockIdx.y;
    const int v = blockIdx.z >> 1, rtile = blockIdx.z & 1;
    const int cnt  = counts[tt];
    const int base = blockIdx.x * 64 + rtile * 32;
    if (base >= cnt) return;
    const int nn = min(32, cnt - base);
    if (t < 32) bl[t] = (t < nn) ? bucket[tt * NNODES + base + t] : -1;
    __syncthreads();

    const float* msrc = v ? m_uni : m_non;

    // stage X and M (32 gathered rows, split fp16, zero-fill inactive)
    for (int q = t; q < 32 * 32; q += 256) {
        int r = q >> 5, c4 = q & 31;
        float4 xv = make_float4(0.f, 0.f, 0.f, 0.f);
        float4 mv = make_float4(0.f, 0.f, 0.f, 0.f);
        int node = bl[r];
        if (node >= 0) {
            xv = *(const float4*)(hin  + (size_t)node * 128 + c4 * 4);
            mv = *(const float4*)(msrc + (size_t)node * 128 + c4 * 4);
        }
        half4 hh, ll;
        hh[0] = hi_(xv.x); ll[0] = lo_(xv.x);
        hh[1] = hi_(xv.y); ll[1] = lo_(xv.y);
        hh[2] = hi_(xv.z); ll[2] = lo_(xv.z);
        hh[3] = hi_(xv.w); ll[3] = lo_(xv.w);
        *(half4*)(Xh + r * PX + c4 * 4) = hh;
        *(half4*)(Xl + r * PX + c4 * 4) = ll;
        hh[0] = hi_(mv.x); ll[0] = lo_(mv.x);
        hh[1] = hi_(mv.y); ll[1] = lo_(mv.y);
        hh[2] = hi_(mv.z); ll[2] = lo_(mv.z);
        hh[3] = hi_(mv.w); ll[3] = lo_(mv.w);
        *(half4*)(Mh + r * PX + c4 * 4) = hh;
        *(half4*)(Ml + r * PX + c4 * 4) = ll;
    }
    __syncthreads();

    const int wave = t >> 6, lane = t & 63, lo = lane & 31, hi = lane >> 5;
    const int d = wave * 32 + lo;
    const int vt = v * NTYPE + tt;
    const _Float16* pih = Wp + (size_t)(vt * 2 + 0) * 98304;
    const _Float16* phh = Wp + (size_t)(vt * 2 + 1) * 98304;

    floatx16 ar = (floatx16)0.0f, az = (floatx16)0.0f;
    floatx16 ax = (floatx16)0.0f, ah = (floatx16)0.0f;

    #pragma unroll 2
    for (int kk = 0; kk < 8; ++kk) {
        int koff = kk * 16 + hi * 8;
        half8 xh = *(const half8*)(Xh + lo * PX + koff);
        half8 xl = *(const half8*)(Xl + lo * PX + koff);
        half8 mh = *(const half8*)(Mh + lo * PX + koff);
        half8 ml = *(const half8*)(Ml + lo * PX + koff);
        const _Float16* ci = pih + (size_t)(kk * 2 + hi) * 6144;
        const _Float16* ch = phh + (size_t)(kk * 2 + hi) * 6144;
        half8 birh = *(const half8*)(ci + (0   + d) * 8);
        half8 birl = *(const half8*)(ci + 3072 + (0   + d) * 8);
        half8 bizh = *(const half8*)(ci + (128 + d) * 8);
        half8 bizl = *(const half8*)(ci + 3072 + (128 + d) * 8);
        half8 binh = *(const half8*)(ci + (256 + d) * 8);
        half8 binl = *(const half8*)(ci + 3072 + (256 + d) * 8);
        half8 bhrh = *(const half8*)(ch + (0   + d) * 8);
        half8 bhrl = *(const half8*)(ch + 3072 + (0   + d) * 8);
        half8 bhzh = *(const half8*)(ch + (128 + d) * 8);
        half8 bhzl = *(const half8*)(ch + 3072 + (128 + d) * 8);
        half8 bhnh = *(const half8*)(ch + (256 + d) * 8);
        half8 bhnl = *(const half8*)(ch + 3072 + (256 + d) * 8);

        ar = __builtin_amdgcn_mfma_f32_32x32x16_f16(xh, birh, ar, 0, 0, 0);
        ar = __builtin_amdgcn_mfma_f32_32x32x16_f16(xh, birl, ar, 0, 0, 0);
        ar = __builtin_amdgcn_mfma_f32_32x32x16_f16(xl, birh, ar, 0, 0, 0);
        ar = __builtin_amdgcn_mfma_f32_32x32x16_f16(mh, bhrh, ar, 0, 0, 0);
        ar = __builtin_amdgcn_mfma_f32_32x32x16_f16(mh, bhrl, ar, 0, 0, 0);
        ar = __builtin_amdgcn_mfma_f32_32x32x16_f16(ml, bhrh, ar, 0, 0, 0);

        az = __builtin_amdgcn_mfma_f32_32x32x16_f16(xh, bizh, az, 0, 0, 0);
        az = __builtin_amdgcn_mfma_f32_32x32x16_f16(xh, bizl, az, 0, 0, 0);
        az = __builtin_amdgcn_mfma_f32_32x32x16_f16(xl, bizh, az, 0, 0, 0);
        az = __builtin_amdgcn_mfma_f32_32x32x16_f16(mh, bhzh, az, 0, 0, 0);
        az = __builtin_amdgcn_mfma_f32_32x32x16_f16(mh, bhzl, az, 0, 0, 0);
        az = __builtin_amdgcn_mfma_f32_32x32x16_f16(ml, bhzh, az, 0, 0, 0);

        ax = __builtin_amdgcn_mfma_f32_32x32x16_f16(xh, binh, ax, 0, 0, 0);
        ax = __builtin_amdgcn_mfma_f32_32x32x16_f16(xh, binl, ax, 0, 0, 0);
        ax = __builtin_amdgcn_mfma_f32_32x32x16_f16(xl, binh, ax, 0, 0, 0);
        ah = __builtin_amdgcn_mfma_f32_32x32x16_f16(mh, bhnh, ah, 0, 0, 0);
        ah = __builtin_amdgcn_mfma_f32_32x32x16_f16(mh, bhnl, ah, 0, 0, 0);
        ah = __builtin_amdgcn_mfma_f32_32x32x16_f16(ml, bhnh, ah, 0, 0, 0);
    }

    const float* bi = bihp + (size_t)vt * 384;
    const float* bh = bhhp + (size_t)vt * 384;
    float b_r  = bi[d] + bh[d];
    float b_z  = bi[128 + d] + bh[128 + d];
    float b_in = bi[256 + d];
    float b_hn = bh[256 + d];
    #pragma unroll
    for (int reg = 0; reg < 16; ++reg) {
        int n = drow_(reg, hi);
        int node = bl[n];
        if (node < 0) continue;
        float r  = sig_(ar[reg] + b_r);
        float z  = sig_(az[reg] + b_z);
        float nv = tanhf(ax[reg] + b_in + r * (ah[reg] + b_hn));
        float mv = msrc[(size_t)node * 128 + d];   // fp32 m for z*m
        atomicAdd(hout + (size_t)node * 128 + d, (1.0f - z) * nv + z * mv);
    }
}

// ---------------------------------------------------------------- launch
extern "C" void kernel_launch(void* const* d_in, const int* in_sizes, int n_in,
                              void* d_out, int out_size, void* d_ws, size_t ws_size,
                              hipStream_t stream) {
    const float* g    = (const float*)d_in[0];
    const float* h    = (const float*)d_in[1];
    const float* msgW = (const float*)d_in[2];
    const float* Wih  = (const float*)d_in[3];
    const float* Whh  = (const float*)d_in[4];
    const float* bih  = (const float*)d_in[5];
    const float* bhh  = (const float*)d_in[6];
    float* h1 = (float*)d_out;

    char* ws = (char*)d_ws;
    float* m_non = (float*)ws;                                   // 8 MB
    float* m_uni = m_non + (size_t)NNODES * 128;                 // 8 MB
    int* counts  = (int*)(ws + 2 * (size_t)NNODES * 128 * 4);
    int* bucket  = counts + 8;                                   // [6][16384]
    _Float16* WpM = (_Float16*)(bucket + NTYPE * NNODES);        // 1,835,008 halves (3.67 MB)
    _Float16* WpG = WpM + (size_t)NBOND * NLAY * 16 * 2048;      // 2,359,296 halves (4.72 MB)
    float* h0 = (float*)(WpG + (size_t)2 * NTYPE * 2 * 98304);   // 8 MB ping-pong h buffer

    (void)hipMemsetAsync(counts, 0, 8 * sizeof(int), stream);
    setup_kernel<<<NNODES * 128 / 256, 256, 0, stream>>>(h, h0, counts, bucket);
    pack_msg_kernel<<<(NBOND * NLAY * 16 * 128 + 255) / 256, 256, 0, stream>>>(msgW, WpM);
    pack_gru_kernel<<<(2 * NTYPE * 2 * 16 * 384 + 255) / 256, 256, 0, stream>>>(Wih, Whh, WpG);

    // h ping-pong: p0 h0->h1(d_out), p1 h1->h0, p2 h0->h1(d_out)
    const float* hin_p[3]  = {h0, h1, h0};
    float*       hout_p[3] = {h1, h0, h1};
    for (int pass = 0; pass < 3; ++pass) {
        (void)hipMemsetAsync(m_non, 0, (size_t)NNODES * 128 * 4, stream);
        (void)hipMemsetAsync(hout_p[pass], 0, (size_t)NNODES * 128 * 4, stream);
        mlp_agg_mfma<<<dim3(NBOND, 128), 256, 0, stream>>>(hin_p[pass], WpM, g, m_non, m_uni);
        gru_mfma<<<dim3(NNODES / 64, NTYPE, 4), 256, 0, stream>>>(hin_p[pass], hout_p[pass],
                                                                  m_non, m_uni, counts, bucket,
                                                                  WpG, bih, bhh);
    }
}

// Round 3
// 801.984 us; speedup vs baseline: 1.1832x; 1.1282x over previous
//
#include <hip/hip_runtime.h>
#include <math.h>

#define NBOND 7
#define NLAY 8
#define NTYPE 6
#define NNODES 16384   // B*N = 128*128
#define PX 136         // LDS pitch in halves (272 B, 16B-aligned; 68 dw % 32 = 4 -> conflict-clean)

typedef _Float16 half8 __attribute__((ext_vector_type(8)));
typedef _Float16 half4 __attribute__((ext_vector_type(4)));
typedef float floatx16 __attribute__((ext_vector_type(16)));

__device__ __forceinline__ float sig_(float x) { return 1.0f / (1.0f + __expf(-x)); }
// D-layout for 32x32 MFMA: col = lane&31, row = (reg&3) + 8*(reg>>2) + 4*(lane>>5)
__device__ __forceinline__ int drow_(int reg, int hi) { return (reg & 3) + 8 * (reg >> 2) + 4 * hi; }

__device__ __forceinline__ _Float16 hi_(float v) { return (_Float16)v; }
__device__ __forceinline__ _Float16 lo_(float v) { return (_Float16)(v - (float)(_Float16)v); }

// ---------------------------------------------------------------- setup
__global__ void setup_kernel(const float* __restrict__ h, float* __restrict__ hT,
                             int* __restrict__ counts, int* __restrict__ bucket)
{
    int gid = blockIdx.x * 256 + threadIdx.x;
    int node = gid >> 7, d = gid & 127;
    hT[gid] = (d < 75) ? h[node * 75 + d] : 0.0f;
    if (gid < NNODES) {
        float a = h[gid * 75];
        int tt = 5;
        if      (a == 6.0f) tt = 0;
        else if (a == 7.0f) tt = 1;
        else if (a == 8.0f) tt = 2;
        else if (a == 9.0f) tt = 3;
        else if (a == 0.0f) tt = 4;
        int slot = atomicAdd(&counts[tt], 1);
        bucket[tt * NNODES + slot] = gid;
    }
}

// ---------------------------------------------------------------- weight packing (fp32 -> split fp16 hi/lo planes)
// msgW: [(kb*8+l)][c 0..15][plane hi/lo][e 0..127][j 0..7]  (j along input dim d)
__global__ void pack_msg_kernel(const float* __restrict__ msgW, _Float16* __restrict__ Wp)
{
    int idx = blockIdx.x * 256 + threadIdx.x;
    if (idx >= NBOND * NLAY * 16 * 128) return;
    int e  = idx & 127;
    int c  = (idx >> 7) & 15;
    int kl = idx >> 11;
    const float* src = msgW + ((size_t)kl * 128 + e) * 128 + c * 8;
    float4 u = *(const float4*)src;
    float4 v = *(const float4*)(src + 4);
    float av[8] = {u.x, u.y, u.z, u.w, v.x, v.y, v.z, v.w};
    half8 hh, ll;
    #pragma unroll
    for (int j = 0; j < 8; ++j) { hh[j] = hi_(av[j]); ll[j] = lo_(av[j]); }
    _Float16* dst = Wp + ((size_t)kl * 16 + c) * 2048;
    *(half8*)(dst + e * 8)        = hh;
    *(half8*)(dst + 1024 + e * 8) = ll;
}

// GRU: [(vt*2+mat)][c 0..15][plane hi/lo][col 0..383][j 0..7]
__global__ void pack_gru_kernel(const float* __restrict__ Wih, const float* __restrict__ Whh,
                                _Float16* __restrict__ Wp)
{
    int idx = blockIdx.x * 256 + threadIdx.x;
    if (idx >= 2 * NTYPE * 2 * 16 * 384) return;
    int col = idx % 384;
    int c   = (idx / 384) & 15;
    int vm  = idx / 6144;       // (vt*2 + mat), vt = v*6+tt
    int mat = vm & 1;
    int vt  = vm >> 1;
    const float* src = (mat ? Whh : Wih) + ((size_t)vt * 384 + col) * 128 + c * 8;
    float4 u = *(const float4*)src;
    float4 v = *(const float4*)(src + 4);
    float av[8] = {u.x, u.y, u.z, u.w, v.x, v.y, v.z, v.w};
    half8 hh, ll;
    #pragma unroll
    for (int j = 0; j < 8; ++j) { hh[j] = hi_(av[j]); ll[j] = lo_(av[j]); }
    _Float16* dst = Wp + (size_t)vm * 98304 + (size_t)c * 6144;
    *(half8*)(dst + col * 8)        = hh;
    *(half8*)(dst + 3072 + col * 8) = ll;
}

// ---------------------------------------------------------------- MLP + aggregation (split-fp16 MFMA)
// One block per (kb, b): 128 nodes resident in LDS through 8 layers.
// COL-STATIONARY waves: wave w owns output col-tile w (cols w*32..+31) for ALL
// 4 row-tiles. Per kk-step: 2 weight loads (L2) feed 12 MFMAs (6:1 ratio, vs
// 1.5:1 row-stationary) and the block reads each layer's weights exactly ONCE
// (64 KB vs 256 KB). A-fragments re-read per row-tile from LDS (cheap).
// 2 barriers/layer (cross-wave WAR/RAW on X) — measured ~free in round 1.
__global__ __launch_bounds__(256) void mlp_agg_mfma(
    const float* __restrict__ hin, const _Float16* __restrict__ Wp,
    const float* __restrict__ gmat, float* __restrict__ m_non, float* __restrict__ m_uni)
{
    __shared__ _Float16 Xhi[128 * PX];
    __shared__ _Float16 Xlo[128 * PX];

    const int t = threadIdx.x;
    const int kb = blockIdx.x, b = blockIdx.y;
    const int wave = t >> 6, lane = t & 63, lo = lane & 31, hi = lane >> 5;
    const int row = wave * 32 + lo;    // agg-phase A row
    const int wcol = wave * 32 + lo;   // MLP-phase output column

    // stage layer-0 activations (fp32 -> hi/lo fp16)
    for (int q = t; q < 128 * 32; q += 256) {
        int r = q >> 5, c4 = q & 31;
        float4 v = *(const float4*)(hin + ((size_t)(b * 128 + r)) * 128 + c4 * 4);
        half4 hh, ll;
        hh[0] = hi_(v.x); ll[0] = lo_(v.x);
        hh[1] = hi_(v.y); ll[1] = lo_(v.y);
        hh[2] = hi_(v.z); ll[2] = lo_(v.z);
        hh[3] = hi_(v.w); ll[3] = lo_(v.w);
        *(half4*)(Xhi + r * PX + c4 * 4) = hh;
        *(half4*)(Xlo + r * PX + c4 * 4) = ll;
    }
    __syncthreads();

    floatx16 acc[4];

    #pragma unroll 1
    for (int l = 0; l < NLAY; ++l) {
        #pragma unroll
        for (int rt = 0; rt < 4; ++rt) acc[rt] = (floatx16)0.0f;
        const _Float16* wb = Wp + ((size_t)(kb * NLAY + l) * 16) * 2048;

        #pragma unroll
        for (int kk = 0; kk < 8; ++kk) {
            const _Float16* bp = wb + (size_t)(kk * 2 + hi) * 2048;
            half8 b_h = *(const half8*)(bp + wcol * 8);
            half8 b_l = *(const half8*)(bp + 1024 + wcol * 8);
            #pragma unroll
            for (int rt = 0; rt < 4; ++rt) {
                half8 a_h = *(const half8*)(Xhi + (rt * 32 + lo) * PX + kk * 16 + hi * 8);
                half8 a_l = *(const half8*)(Xlo + (rt * 32 + lo) * PX + kk * 16 + hi * 8);
                acc[rt] = __builtin_amdgcn_mfma_f32_32x32x16_f16(a_h, b_h, acc[rt], 0, 0, 0);
                acc[rt] = __builtin_amdgcn_mfma_f32_32x32x16_f16(a_h, b_l, acc[rt], 0, 0, 0);
                acc[rt] = __builtin_amdgcn_mfma_f32_32x32x16_f16(a_l, b_h, acc[rt], 0, 0, 0);
            }
        }
        __syncthreads();   // all waves' X reads for layer l done

        if (l < NLAY - 1) {
            // writeback: fixed column wcol, rows rt*32+drow (cross-row, own column)
            #pragma unroll
            for (int rt = 0; rt < 4; ++rt)
                #pragma unroll
                for (int reg = 0; reg < 16; ++reg) {
                    int n = rt * 32 + drow_(reg, hi);
                    float vv = fmaxf(acc[rt][reg], 0.0f);
                    Xhi[n * PX + wcol] = hi_(vv);
                    Xlo[n * PX + wcol] = lo_(vv);
                }
        } else {
            // final layer: Xt[e][m]; lane's fixed dim IS e=wcol -> contiguous half4 in m
            #pragma unroll
            for (int rt = 0; rt < 4; ++rt)
                #pragma unroll
                for (int s = 0; s < 4; ++s) {
                    int m0 = rt * 32 + 8 * s + 4 * hi;
                    half4 hh, ll;
                    #pragma unroll
                    for (int j = 0; j < 4; ++j) {
                        float vv = acc[rt][4 * s + j];
                        hh[j] = hi_(vv); ll[j] = lo_(vv);
                    }
                    *(half4*)(Xhi + wcol * PX + m0) = hh;
                    *(half4*)(Xlo + wcol * PX + m0) = ll;
                }
        }
        __syncthreads();
    }

    // ---- aggregation: m[n][d] = sum_m g[b,kb,n,m]*xb[m][d]; A = g (inline split), B = Xt ----
    // row-stationary again: wave owns rows wave*32..+31, all 4 col-tiles of Xt (LDS).
    #pragma unroll
    for (int ct = 0; ct < 4; ++ct) acc[ct] = (floatx16)0.0f;
    const float* grow = gmat + (size_t)(b * NBOND + kb) * 16384;

    #pragma unroll 2
    for (int kk = 0; kk < 8; ++kk) {
        const float* gp = grow + (size_t)row * 128 + kk * 16 + hi * 8;
        float4 u = *(const float4*)gp, v2 = *(const float4*)(gp + 4);
        float av[8] = {u.x, u.y, u.z, u.w, v2.x, v2.y, v2.z, v2.w};
        half8 a_h, a_l;
        #pragma unroll
        for (int j = 0; j < 8; ++j) { a_h[j] = hi_(av[j]); a_l[j] = lo_(av[j]); }
        #pragma unroll
        for (int ct = 0; ct < 4; ++ct) {
            half8 b_h = *(const half8*)(Xhi + (ct * 32 + lo) * PX + kk * 16 + hi * 8);
            half8 b_l = *(const half8*)(Xlo + (ct * 32 + lo) * PX + kk * 16 + hi * 8);
            acc[ct] = __builtin_amdgcn_mfma_f32_32x32x16_f16(a_h, b_h, acc[ct], 0, 0, 0);
            acc[ct] = __builtin_amdgcn_mfma_f32_32x32x16_f16(a_h, b_l, acc[ct], 0, 0, 0);
            acc[ct] = __builtin_amdgcn_mfma_f32_32x32x16_f16(a_l, b_h, acc[ct], 0, 0, 0);
        }
    }

    if (kb == NBOND - 1) {
        #pragma unroll
        for (int ct = 0; ct < 4; ++ct)
            #pragma unroll
            for (int reg = 0; reg < 16; ++reg) {
                int n = wave * 32 + drow_(reg, hi);
                m_uni[((size_t)(b * 128 + n)) * 128 + ct * 32 + lo] = acc[ct][reg];
            }
    } else {
        #pragma unroll
        for (int ct = 0; ct < 4; ++ct)
            #pragma unroll
            for (int reg = 0; reg < 16; ++reg) {
                int n = wave * 32 + drow_(reg, hi);
                atomicAdd(m_non + ((size_t)(b * 128 + n)) * 128 + ct * 32 + lo, acc[ct][reg]);
            }
    }
}

// ---------------------------------------------------------------- grouped GRU (split-fp16 MFMA)
// One block = 32 gathered nodes of one type, BOTH GRU variants (v-loop, M
// restaged per v). LDS 35 KB -> up to 4 blocks/CU. Block owns its 32 nodes
// exclusively -> in-place update of hT: v=0 stores, v=1 read-add-stores.
// No atomics, no ping-pong, no hout memset.
__global__ __launch_bounds__(256, 3) void gru_mfma(
    float* __restrict__ hT,
    const float* __restrict__ m_non, const float* __restrict__ m_uni,
    const int* __restrict__ counts, const int* __restrict__ bucket,
    const _Float16* __restrict__ Wp, const float* __restrict__ bihp, const float* __restrict__ bhhp)
{
    __shared__ _Float16 Xh[32 * PX], Xl[32 * PX], Mh[32 * PX], Ml[32 * PX];
    __shared__ int bl[32];

    const int t = threadIdx.x, tt = blockIdx.y, rtile = blockIdx.z;
    const int cnt  = counts[tt];
    const int base = blockIdx.x * 64 + rtile * 32;
    if (base >= cnt) return;
    const int nn = min(32, cnt - base);
    if (t < 32) bl[t] = (t < nn) ? bucket[tt * NNODES + base + t] : -1;
    __syncthreads();

    // stage X once (gathered h rows, split fp16, zero-fill inactive)
    for (int q = t; q < 32 * 32; q += 256) {
        int r = q >> 5, c4 = q & 31;
        float4 xv = make_float4(0.f, 0.f, 0.f, 0.f);
        int node = bl[r];
        if (node >= 0) xv = *(const float4*)(hT + (size_t)node * 128 + c4 * 4);
        half4 hh, ll;
        hh[0] = hi_(xv.x); ll[0] = lo_(xv.x);
        hh[1] = hi_(xv.y); ll[1] = lo_(xv.y);
        hh[2] = hi_(xv.z); ll[2] = lo_(xv.z);
        hh[3] = hi_(xv.w); ll[3] = lo_(xv.w);
        *(half4*)(Xh + r * PX + c4 * 4) = hh;
        *(half4*)(Xl + r * PX + c4 * 4) = ll;
    }

    const int wave = t >> 6, lane = t & 63, lo = lane & 31, hi = lane >> 5;
    const int d = wave * 32 + lo;

    #pragma unroll 1
    for (int v = 0; v < 2; ++v) {
        const float* msrc = v ? m_uni : m_non;
        __syncthreads();   // v=0: X-stage commit; v=1: prior M readers done
        for (int q = t; q < 32 * 32; q += 256) {
            int r = q >> 5, c4 = q & 31;
            float4 mv = make_float4(0.f, 0.f, 0.f, 0.f);
            int node = bl[r];
            if (node >= 0) mv = *(const float4*)(msrc + (size_t)node * 128 + c4 * 4);
            half4 hh, ll;
            hh[0] = hi_(mv.x); ll[0] = lo_(mv.x);
            hh[1] = hi_(mv.y); ll[1] = lo_(mv.y);
            hh[2] = hi_(mv.z); ll[2] = lo_(mv.z);
            hh[3] = hi_(mv.w); ll[3] = lo_(mv.w);
            *(half4*)(Mh + r * PX + c4 * 4) = hh;
            *(half4*)(Ml + r * PX + c4 * 4) = ll;
        }
        __syncthreads();

        const int vt = v * NTYPE + tt;
        const _Float16* pih = Wp + (size_t)(vt * 2 + 0) * 98304;
        const _Float16* phh = Wp + (size_t)(vt * 2 + 1) * 98304;

        floatx16 ar = (floatx16)0.0f, az = (floatx16)0.0f;
        floatx16 ax = (floatx16)0.0f, ah = (floatx16)0.0f;

        #pragma unroll 2
        for (int kk = 0; kk < 8; ++kk) {
            int koff = kk * 16 + hi * 8;
            half8 xh = *(const half8*)(Xh + lo * PX + koff);
            half8 xl = *(const half8*)(Xl + lo * PX + koff);
            half8 mh = *(const half8*)(Mh + lo * PX + koff);
            half8 ml = *(const half8*)(Ml + lo * PX + koff);
            const _Float16* ci = pih + (size_t)(kk * 2 + hi) * 6144;
            const _Float16* ch = phh + (size_t)(kk * 2 + hi) * 6144;
            half8 birh = *(const half8*)(ci + (0   + d) * 8);
            half8 birl = *(const half8*)(ci + 3072 + (0   + d) * 8);
            half8 bizh = *(const half8*)(ci + (128 + d) * 8);
            half8 bizl = *(const half8*)(ci + 3072 + (128 + d) * 8);
            half8 binh = *(const half8*)(ci + (256 + d) * 8);
            half8 binl = *(const half8*)(ci + 3072 + (256 + d) * 8);
            half8 bhrh = *(const half8*)(ch + (0   + d) * 8);
            half8 bhrl = *(const half8*)(ch + 3072 + (0   + d) * 8);
            half8 bhzh = *(const half8*)(ch + (128 + d) * 8);
            half8 bhzl = *(const half8*)(ch + 3072 + (128 + d) * 8);
            half8 bhnh = *(const half8*)(ch + (256 + d) * 8);
            half8 bhnl = *(const half8*)(ch + 3072 + (256 + d) * 8);

            ar = __builtin_amdgcn_mfma_f32_32x32x16_f16(xh, birh, ar, 0, 0, 0);
            ar = __builtin_amdgcn_mfma_f32_32x32x16_f16(xh, birl, ar, 0, 0, 0);
            ar = __builtin_amdgcn_mfma_f32_32x32x16_f16(xl, birh, ar, 0, 0, 0);
            ar = __builtin_amdgcn_mfma_f32_32x32x16_f16(mh, bhrh, ar, 0, 0, 0);
            ar = __builtin_amdgcn_mfma_f32_32x32x16_f16(mh, bhrl, ar, 0, 0, 0);
            ar = __builtin_amdgcn_mfma_f32_32x32x16_f16(ml, bhrh, ar, 0, 0, 0);

            az = __builtin_amdgcn_mfma_f32_32x32x16_f16(xh, bizh, az, 0, 0, 0);
            az = __builtin_amdgcn_mfma_f32_32x32x16_f16(xh, bizl, az, 0, 0, 0);
            az = __builtin_amdgcn_mfma_f32_32x32x16_f16(xl, bizh, az, 0, 0, 0);
            az = __builtin_amdgcn_mfma_f32_32x32x16_f16(mh, bhzh, az, 0, 0, 0);
            az = __builtin_amdgcn_mfma_f32_32x32x16_f16(mh, bhzl, az, 0, 0, 0);
            az = __builtin_amdgcn_mfma_f32_32x32x16_f16(ml, bhzh, az, 0, 0, 0);

            ax = __builtin_amdgcn_mfma_f32_32x32x16_f16(xh, binh, ax, 0, 0, 0);
            ax = __builtin_amdgcn_mfma_f32_32x32x16_f16(xh, binl, ax, 0, 0, 0);
            ax = __builtin_amdgcn_mfma_f32_32x32x16_f16(xl, binh, ax, 0, 0, 0);
            ah = __builtin_amdgcn_mfma_f32_32x32x16_f16(mh, bhnh, ah, 0, 0, 0);
            ah = __builtin_amdgcn_mfma_f32_32x32x16_f16(mh, bhnl, ah, 0, 0, 0);
            ah = __builtin_amdgcn_mfma_f32_32x32x16_f16(ml, bhnh, ah, 0, 0, 0);
        }

        const float* bi = bihp + (size_t)vt * 384;
        const float* bh = bhhp + (size_t)vt * 384;
        float b_r  = bi[d] + bh[d];
        float b_z  = bi[128 + d] + bh[128 + d];
        float b_in = bi[256 + d];
        float b_hn = bh[256 + d];
        #pragma unroll
        for (int reg = 0; reg < 16; ++reg) {
            int n = drow_(reg, hi);
            int node = bl[n];
            if (node < 0) continue;
            float r  = sig_(ar[reg] + b_r);
            float z  = sig_(az[reg] + b_z);
            float nv = tanhf(ax[reg] + b_in + r * (ah[reg] + b_hn));
            float mv = msrc[(size_t)node * 128 + d];   // fp32 m for z*m
            float val = (1.0f - z) * nv + z * mv;
            if (v == 0) hT[(size_t)node * 128 + d] = val;                       // overwrite old h
            else        hT[(size_t)node * 128 + d] += val;                      // block owns node
        }
    }
}

// ---------------------------------------------------------------- launch
extern "C" void kernel_launch(void* const* d_in, const int* in_sizes, int n_in,
                              void* d_out, int out_size, void* d_ws, size_t ws_size,
                              hipStream_t stream) {
    const float* g    = (const float*)d_in[0];
    const float* h    = (const float*)d_in[1];
    const float* msgW = (const float*)d_in[2];
    const float* Wih  = (const float*)d_in[3];
    const float* Whh  = (const float*)d_in[4];
    const float* bih  = (const float*)d_in[5];
    const float* bhh  = (const float*)d_in[6];
    float* hT = (float*)d_out;

    char* ws = (char*)d_ws;
    float* m_non = (float*)ws;                                   // 8 MB
    float* m_uni = m_non + (size_t)NNODES * 128;                 // 8 MB
    int* counts  = (int*)(ws + 2 * (size_t)NNODES * 128 * 4);
    int* bucket  = counts + 8;                                   // [6][16384]
    _Float16* WpM = (_Float16*)(bucket + NTYPE * NNODES);        // 1,835,008 halves (3.67 MB)
    _Float16* WpG = WpM + (size_t)NBOND * NLAY * 16 * 2048;      // 2,359,296 halves (4.72 MB)

    (void)hipMemsetAsync(counts, 0, 8 * sizeof(int), stream);
    setup_kernel<<<NNODES * 128 / 256, 256, 0, stream>>>(h, hT, counts, bucket);
    pack_msg_kernel<<<(NBOND * NLAY * 16 * 128 + 255) / 256, 256, 0, stream>>>(msgW, WpM);
    pack_gru_kernel<<<(2 * NTYPE * 2 * 16 * 384 + 255) / 256, 256, 0, stream>>>(Wih, Whh, WpG);

    for (int pass = 0; pass < 3; ++pass) {
        (void)hipMemsetAsync(m_non, 0, (size_t)NNODES * 128 * 4, stream);
        mlp_agg_mfma<<<dim3(NBOND, 128), 256, 0, stream>>>(hT, WpM, g, m_non, m_uni);
        gru_mfma<<<dim3(NNODES / 64, NTYPE, 2), 256, 0, stream>>>(hT, m_non, m_uni, counts, bucket,
                                                                  WpG, bih, bhh);
    }
}

// Round 4
// 778.825 us; speedup vs baseline: 1.2184x; 1.0297x over previous
//
#include <hip/hip_runtime.h>
#include <math.h>

#define NBOND 7
#define NLAY 8
#define NTYPE 6
#define NNODES 16384   // B*N = 128*128
#define PX 136         // LDS pitch in halves (272 B, 16B-aligned; 68 dw % 32 = 4 -> conflict-clean)

typedef _Float16 half8 __attribute__((ext_vector_type(8)));
typedef _Float16 half4 __attribute__((ext_vector_type(4)));
typedef float floatx16 __attribute__((ext_vector_type(16)));

__device__ __forceinline__ float sig_(float x) { return 1.0f / (1.0f + __expf(-x)); }
// D-layout for 32x32 MFMA: col = lane&31, row = (reg&3) + 8*(reg>>2) + 4*(lane>>5)
__device__ __forceinline__ int drow_(int reg, int hi) { return (reg & 3) + 8 * (reg >> 2) + 4 * hi; }

__device__ __forceinline__ _Float16 hi_(float v) { return (_Float16)v; }
__device__ __forceinline__ _Float16 lo_(float v) { return (_Float16)(v - (float)(_Float16)v); }

// ---------------------------------------------------------------- setup
__global__ void setup_kernel(const float* __restrict__ h, float* __restrict__ hT,
                             int* __restrict__ counts, int* __restrict__ bucket)
{
    int gid = blockIdx.x * 256 + threadIdx.x;
    int node = gid >> 7, d = gid & 127;
    hT[gid] = (d < 75) ? h[node * 75 + d] : 0.0f;
    if (gid < NNODES) {
        float a = h[gid * 75];
        int tt = 5;
        if      (a == 6.0f) tt = 0;
        else if (a == 7.0f) tt = 1;
        else if (a == 8.0f) tt = 2;
        else if (a == 9.0f) tt = 3;
        else if (a == 0.0f) tt = 4;
        int slot = atomicAdd(&counts[tt], 1);
        bucket[tt * NNODES + slot] = gid;
    }
}

// ---------------------------------------------------------------- weight packing (fp32 -> split fp16 hi/lo planes)
// msgW: [(kb*8+l)][c 0..15][plane hi/lo][e 0..127][j 0..7]  (j along input dim d)
__global__ void pack_msg_kernel(const float* __restrict__ msgW, _Float16* __restrict__ Wp)
{
    int idx = blockIdx.x * 256 + threadIdx.x;
    if (idx >= NBOND * NLAY * 16 * 128) return;
    int e  = idx & 127;
    int c  = (idx >> 7) & 15;
    int kl = idx >> 11;
    const float* src = msgW + ((size_t)kl * 128 + e) * 128 + c * 8;
    float4 u = *(const float4*)src;
    float4 v = *(const float4*)(src + 4);
    float av[8] = {u.x, u.y, u.z, u.w, v.x, v.y, v.z, v.w};
    half8 hh, ll;
    #pragma unroll
    for (int j = 0; j < 8; ++j) { hh[j] = hi_(av[j]); ll[j] = lo_(av[j]); }
    _Float16* dst = Wp + ((size_t)kl * 16 + c) * 2048;
    *(half8*)(dst + e * 8)        = hh;
    *(half8*)(dst + 1024 + e * 8) = ll;
}

// GRU: [(vt*2+mat)][c 0..15][plane hi/lo][col 0..383][j 0..7]
__global__ void pack_gru_kernel(const float* __restrict__ Wih, const float* __restrict__ Whh,
                                _Float16* __restrict__ Wp)
{
    int idx = blockIdx.x * 256 + threadIdx.x;
    if (idx >= 2 * NTYPE * 2 * 16 * 384) return;
    int col = idx % 384;
    int c   = (idx / 384) & 15;
    int vm  = idx / 6144;       // (vt*2 + mat), vt = v*6+tt
    int mat = vm & 1;
    int vt  = vm >> 1;
    const float* src = (mat ? Whh : Wih) + ((size_t)vt * 384 + col) * 128 + c * 8;
    float4 u = *(const float4*)src;
    float4 v = *(const float4*)(src + 4);
    float av[8] = {u.x, u.y, u.z, u.w, v.x, v.y, v.z, v.w};
    half8 hh, ll;
    #pragma unroll
    for (int j = 0; j < 8; ++j) { hh[j] = hi_(av[j]); ll[j] = lo_(av[j]); }
    _Float16* dst = Wp + (size_t)vm * 98304 + (size_t)c * 6144;
    *(half8*)(dst + col * 8)        = hh;
    *(half8*)(dst + 3072 + col * 8) = ll;
}

// ---------------------------------------------------------------- MLP + aggregation (split-fp16 MFMA)
// One block per (kb, b): 128 nodes resident in LDS through 8 layers.
// 512 threads / 8 waves over the SAME 68 KB tile -> 2 blocks/CU keeps LDS fit
// and gives 4 waves/SIMD (vs 2) for latency hiding.
// MLP phase: wave w = (col-tile w&3) x (row-half w>>2): per kk 2 weight loads
// feed 6 MFMAs; weights read 2x/block (L2-resident).
// Agg phase: wave w = (row-tile w&3) x (col-half w>>2).
__global__ __launch_bounds__(512, 4) void mlp_agg_mfma(
    const float* __restrict__ hin, const _Float16* __restrict__ Wp,
    const float* __restrict__ gmat, float* __restrict__ m_non, float* __restrict__ m_uni)
{
    __shared__ _Float16 Xhi[128 * PX];
    __shared__ _Float16 Xlo[128 * PX];

    const int t = threadIdx.x;
    const int kb = blockIdx.x, b = blockIdx.y;
    const int wave = t >> 6, lane = t & 63, lo = lane & 31, hi = lane >> 5;
    const int ctw = wave & 3, rh = wave >> 2;   // MLP: col-tile, row-half
    const int wcol = ctw * 32 + lo;             // MLP-phase output column

    // stage layer-0 activations (fp32 -> hi/lo fp16)
    for (int q = t; q < 128 * 32; q += 512) {
        int r = q >> 5, c4 = q & 31;
        float4 v = *(const float4*)(hin + ((size_t)(b * 128 + r)) * 128 + c4 * 4);
        half4 hh, ll;
        hh[0] = hi_(v.x); ll[0] = lo_(v.x);
        hh[1] = hi_(v.y); ll[1] = lo_(v.y);
        hh[2] = hi_(v.z); ll[2] = lo_(v.z);
        hh[3] = hi_(v.w); ll[3] = lo_(v.w);
        *(half4*)(Xhi + r * PX + c4 * 4) = hh;
        *(half4*)(Xlo + r * PX + c4 * 4) = ll;
    }
    __syncthreads();

    floatx16 acc[2];

    #pragma unroll 1
    for (int l = 0; l < NLAY; ++l) {
        #pragma unroll
        for (int r2 = 0; r2 < 2; ++r2) acc[r2] = (floatx16)0.0f;
        const _Float16* wb = Wp + ((size_t)(kb * NLAY + l) * 16) * 2048;

        #pragma unroll
        for (int kk = 0; kk < 8; ++kk) {
            const _Float16* bp = wb + (size_t)(kk * 2 + hi) * 2048;
            half8 b_h = *(const half8*)(bp + wcol * 8);
            half8 b_l = *(const half8*)(bp + 1024 + wcol * 8);
            #pragma unroll
            for (int r2 = 0; r2 < 2; ++r2) {
                int rrow = (rh * 2 + r2) * 32 + lo;
                half8 a_h = *(const half8*)(Xhi + rrow * PX + kk * 16 + hi * 8);
                half8 a_l = *(const half8*)(Xlo + rrow * PX + kk * 16 + hi * 8);
                acc[r2] = __builtin_amdgcn_mfma_f32_32x32x16_f16(a_h, b_h, acc[r2], 0, 0, 0);
                acc[r2] = __builtin_amdgcn_mfma_f32_32x32x16_f16(a_h, b_l, acc[r2], 0, 0, 0);
                acc[r2] = __builtin_amdgcn_mfma_f32_32x32x16_f16(a_l, b_h, acc[r2], 0, 0, 0);
            }
        }
        __syncthreads();   // all waves' X reads for layer l done

        if (l < NLAY - 1) {
            // writeback: fixed column wcol, rows (rh*2+r2)*32+drow
            #pragma unroll
            for (int r2 = 0; r2 < 2; ++r2)
                #pragma unroll
                for (int reg = 0; reg < 16; ++reg) {
                    int n = (rh * 2 + r2) * 32 + drow_(reg, hi);
                    float vv = fmaxf(acc[r2][reg], 0.0f);
                    Xhi[n * PX + wcol] = hi_(vv);
                    Xlo[n * PX + wcol] = lo_(vv);
                }
        } else {
            // final layer: Xt[e][m]; lane's fixed dim IS e=wcol -> contiguous half4 in m
            #pragma unroll
            for (int r2 = 0; r2 < 2; ++r2)
                #pragma unroll
                for (int s = 0; s < 4; ++s) {
                    int m0 = (rh * 2 + r2) * 32 + 8 * s + 4 * hi;
                    half4 hh, ll;
                    #pragma unroll
                    for (int j = 0; j < 4; ++j) {
                        float vv = acc[r2][4 * s + j];
                        hh[j] = hi_(vv); ll[j] = lo_(vv);
                    }
                    *(half4*)(Xhi + wcol * PX + m0) = hh;
                    *(half4*)(Xlo + wcol * PX + m0) = ll;
                }
        }
        __syncthreads();
    }

    // ---- aggregation: m[n][d] = sum_m g[b,kb,n,m]*xb[m][d]; A = g (inline split), B = Xt ----
    // wave w = (row-tile w&3) x (col-half w>>2); g rows duplicated across col-halves (L2-hit).
    const int rtw = wave & 3, ch = wave >> 2;
    const int row = rtw * 32 + lo;
    #pragma unroll
    for (int c2 = 0; c2 < 2; ++c2) acc[c2] = (floatx16)0.0f;
    const float* grow = gmat + (size_t)(b * NBOND + kb) * 16384;

    #pragma unroll 2
    for (int kk = 0; kk < 8; ++kk) {
        const float* gp = grow + (size_t)row * 128 + kk * 16 + hi * 8;
        float4 u = *(const float4*)gp, v2 = *(const float4*)(gp + 4);
        float av[8] = {u.x, u.y, u.z, u.w, v2.x, v2.y, v2.z, v2.w};
        half8 a_h, a_l;
        #pragma unroll
        for (int j = 0; j < 8; ++j) { a_h[j] = hi_(av[j]); a_l[j] = lo_(av[j]); }
        #pragma unroll
        for (int c2 = 0; c2 < 2; ++c2) {
            int ct = ch * 2 + c2;
            half8 b_h = *(const half8*)(Xhi + (ct * 32 + lo) * PX + kk * 16 + hi * 8);
            half8 b_l = *(const half8*)(Xlo + (ct * 32 + lo) * PX + kk * 16 + hi * 8);
            acc[c2] = __builtin_amdgcn_mfma_f32_32x32x16_f16(a_h, b_h, acc[c2], 0, 0, 0);
            acc[c2] = __builtin_amdgcn_mfma_f32_32x32x16_f16(a_h, b_l, acc[c2], 0, 0, 0);
            acc[c2] = __builtin_amdgcn_mfma_f32_32x32x16_f16(a_l, b_h, acc[c2], 0, 0, 0);
        }
    }

    if (kb == NBOND - 1) {
        #pragma unroll
        for (int c2 = 0; c2 < 2; ++c2)
            #pragma unroll
            for (int reg = 0; reg < 16; ++reg) {
                int n = rtw * 32 + drow_(reg, hi);
                m_uni[((size_t)(b * 128 + n)) * 128 + (ch * 2 + c2) * 32 + lo] = acc[c2][reg];
            }
    } else {
        #pragma unroll
        for (int c2 = 0; c2 < 2; ++c2)
            #pragma unroll
            for (int reg = 0; reg < 16; ++reg) {
                int n = rtw * 32 + drow_(reg, hi);
                atomicAdd(m_non + ((size_t)(b * 128 + n)) * 128 + (ch * 2 + c2) * 32 + lo,
                          acc[c2][reg]);
            }
    }
}

// ---------------------------------------------------------------- grouped GRU (split-fp16 MFMA)
// One block = 32 gathered nodes of one type, BOTH GRU variants (v-loop, M
// restaged per v). LDS 35 KB -> up to 4 blocks/CU. Block owns its 32 nodes
// exclusively -> in-place update of hT: v=0 stores, v=1 read-add-stores.
// No atomics, no ping-pong, no hout memset.
__global__ __launch_bounds__(256, 3) void gru_mfma(
    float* __restrict__ hT,
    const float* __restrict__ m_non, const float* __restrict__ m_uni,
    const int* __restrict__ counts, const int* __restrict__ bucket,
    const _Float16* __restrict__ Wp, const float* __restrict__ bihp, const float* __restrict__ bhhp)
{
    __shared__ _Float16 Xh[32 * PX], Xl[32 * PX], Mh[32 * PX], Ml[32 * PX];
    __shared__ int bl[32];

    const int t = threadIdx.x, tt = blockIdx.y, rtile = blockIdx.z;
    const int cnt  = counts[tt];
    const int base = blockIdx.x * 64 + rtile * 32;
    if (base >= cnt) return;
    const int nn = min(32, cnt - base);
    if (t < 32) bl[t] = (t < nn) ? bucket[tt * NNODES + base + t] : -1;
    __syncthreads();

    // stage X once (gathered h rows, split fp16, zero-fill inactive)
    for (int q = t; q < 32 * 32; q += 256) {
        int r = q >> 5, c4 = q & 31;
        float4 xv = make_float4(0.f, 0.f, 0.f, 0.f);
        int node = bl[r];
        if (node >= 0) xv = *(const float4*)(hT + (size_t)node * 128 + c4 * 4);
        half4 hh, ll;
        hh[0] = hi_(xv.x); ll[0] = lo_(xv.x);
        hh[1] = hi_(xv.y); ll[1] = lo_(xv.y);
        hh[2] = hi_(xv.z); ll[2] = lo_(xv.z);
        hh[3] = hi_(xv.w); ll[3] = lo_(xv.w);
        *(half4*)(Xh + r * PX + c4 * 4) = hh;
        *(half4*)(Xl + r * PX + c4 * 4) = ll;
    }

    const int wave = t >> 6, lane = t & 63, lo = lane & 31, hi = lane >> 5;
    const int d = wave * 32 + lo;

    #pragma unroll 1
    for (int v = 0; v < 2; ++v) {
        const float* msrc = v ? m_uni : m_non;
        __syncthreads();   // v=0: X-stage commit; v=1: prior M readers done
        for (int q = t; q < 32 * 32; q += 256) {
            int r = q >> 5, c4 = q & 31;
            float4 mv = make_float4(0.f, 0.f, 0.f, 0.f);
            int node = bl[r];
            if (node >= 0) mv = *(const float4*)(msrc + (size_t)node * 128 + c4 * 4);
            half4 hh, ll;
            hh[0] = hi_(mv.x); ll[0] = lo_(mv.x);
            hh[1] = hi_(mv.y); ll[1] = lo_(mv.y);
            hh[2] = hi_(mv.z); ll[2] = lo_(mv.z);
            hh[3] = hi_(mv.w); ll[3] = lo_(mv.w);
            *(half4*)(Mh + r * PX + c4 * 4) = hh;
            *(half4*)(Ml + r * PX + c4 * 4) = ll;
        }
        __syncthreads();

        const int vt = v * NTYPE + tt;
        const _Float16* pih = Wp + (size_t)(vt * 2 + 0) * 98304;
        const _Float16* phh = Wp + (size_t)(vt * 2 + 1) * 98304;

        floatx16 ar = (floatx16)0.0f, az = (floatx16)0.0f;
        floatx16 ax = (floatx16)0.0f, ah = (floatx16)0.0f;

        #pragma unroll 2
        for (int kk = 0; kk < 8; ++kk) {
            int koff = kk * 16 + hi * 8;
            half8 xh = *(const half8*)(Xh + lo * PX + koff);
            half8 xl = *(const half8*)(Xl + lo * PX + koff);
            half8 mh = *(const half8*)(Mh + lo * PX + koff);
            half8 ml = *(const half8*)(Ml + lo * PX + koff);
            const _Float16* ci = pih + (size_t)(kk * 2 + hi) * 6144;
            const _Float16* ch = phh + (size_t)(kk * 2 + hi) * 6144;
            half8 birh = *(const half8*)(ci + (0   + d) * 8);
            half8 birl = *(const half8*)(ci + 3072 + (0   + d) * 8);
            half8 bizh = *(const half8*)(ci + (128 + d) * 8);
            half8 bizl = *(const half8*)(ci + 3072 + (128 + d) * 8);
            half8 binh = *(const half8*)(ci + (256 + d) * 8);
            half8 binl = *(const half8*)(ci + 3072 + (256 + d) * 8);
            half8 bhrh = *(const half8*)(ch + (0   + d) * 8);
            half8 bhrl = *(const half8*)(ch + 3072 + (0   + d) * 8);
            half8 bhzh = *(const half8*)(ch + (128 + d) * 8);
            half8 bhzl = *(const half8*)(ch + 3072 + (128 + d) * 8);
            half8 bhnh = *(const half8*)(ch + (256 + d) * 8);
            half8 bhnl = *(const half8*)(ch + 3072 + (256 + d) * 8);

            ar = __builtin_amdgcn_mfma_f32_32x32x16_f16(xh, birh, ar, 0, 0, 0);
            ar = __builtin_amdgcn_mfma_f32_32x32x16_f16(xh, birl, ar, 0, 0, 0);
            ar = __builtin_amdgcn_mfma_f32_32x32x16_f16(xl, birh, ar, 0, 0, 0);
            ar = __builtin_amdgcn_mfma_f32_32x32x16_f16(mh, bhrh, ar, 0, 0, 0);
            ar = __builtin_amdgcn_mfma_f32_32x32x16_f16(mh, bhrl, ar, 0, 0, 0);
            ar = __builtin_amdgcn_mfma_f32_32x32x16_f16(ml, bhrh, ar, 0, 0, 0);

            az = __builtin_amdgcn_mfma_f32_32x32x16_f16(xh, bizh, az, 0, 0, 0);
            az = __builtin_amdgcn_mfma_f32_32x32x16_f16(xh, bizl, az, 0, 0, 0);
            az = __builtin_amdgcn_mfma_f32_32x32x16_f16(xl, bizh, az, 0, 0, 0);
            az = __builtin_amdgcn_mfma_f32_32x32x16_f16(mh, bhzh, az, 0, 0, 0);
            az = __builtin_amdgcn_mfma_f32_32x32x16_f16(mh, bhzl, az, 0, 0, 0);
            az = __builtin_amdgcn_mfma_f32_32x32x16_f16(ml, bhzh, az, 0, 0, 0);

            ax = __builtin_amdgcn_mfma_f32_32x32x16_f16(xh, binh, ax, 0, 0, 0);
            ax = __builtin_amdgcn_mfma_f32_32x32x16_f16(xh, binl, ax, 0, 0, 0);
            ax = __builtin_amdgcn_mfma_f32_32x32x16_f16(xl, binh, ax, 0, 0, 0);
            ah = __builtin_amdgcn_mfma_f32_32x32x16_f16(mh, bhnh, ah, 0, 0, 0);
            ah = __builtin_amdgcn_mfma_f32_32x32x16_f16(mh, bhnl, ah, 0, 0, 0);
            ah = __builtin_amdgcn_mfma_f32_32x32x16_f16(ml, bhnh, ah, 0, 0, 0);
        }

        const float* bi = bihp + (size_t)vt * 384;
        const float* bh = bhhp + (size_t)vt * 384;
        float b_r  = bi[d] + bh[d];
        float b_z  = bi[128 + d] + bh[128 + d];
        float b_in = bi[256 + d];
        float b_hn = bh[256 + d];
        #pragma unroll
        for (int reg = 0; reg < 16; ++reg) {
            int n = drow_(reg, hi);
            int node = bl[n];
            if (node < 0) continue;
            float r  = sig_(ar[reg] + b_r);
            float z  = sig_(az[reg] + b_z);
            float nv = tanhf(ax[reg] + b_in + r * (ah[reg] + b_hn));
            float mv = msrc[(size_t)node * 128 + d];   // fp32 m for z*m
            float val = (1.0f - z) * nv + z * mv;
            if (v == 0) hT[(size_t)node * 128 + d] = val;                       // overwrite old h
            else        hT[(size_t)node * 128 + d] += val;                      // block owns node
        }
    }
}

// ---------------------------------------------------------------- launch
extern "C" void kernel_launch(void* const* d_in, const int* in_sizes, int n_in,
                              void* d_out, int out_size, void* d_ws, size_t ws_size,
                              hipStream_t stream) {
    const float* g    = (const float*)d_in[0];
    const float* h    = (const float*)d_in[1];
    const float* msgW = (const float*)d_in[2];
    const float* Wih  = (const float*)d_in[3];
    const float* Whh  = (const float*)d_in[4];
    const float* bih  = (const float*)d_in[5];
    const float* bhh  = (const float*)d_in[6];
    float* hT = (float*)d_out;

    char* ws = (char*)d_ws;
    float* m_non = (float*)ws;                                   // 8 MB
    float* m_uni = m_non + (size_t)NNODES * 128;                 // 8 MB
    int* counts  = (int*)(ws + 2 * (size_t)NNODES * 128 * 4);
    int* bucket  = counts + 8;                                   // [6][16384]
    _Float16* WpM = (_Float16*)(bucket + NTYPE * NNODES);        // 1,835,008 halves (3.67 MB)
    _Float16* WpG = WpM + (size_t)NBOND * NLAY * 16 * 2048;      // 2,359,296 halves (4.72 MB)

    (void)hipMemsetAsync(counts, 0, 8 * sizeof(int), stream);
    setup_kernel<<<NNODES * 128 / 256, 256, 0, stream>>>(h, hT, counts, bucket);
    pack_msg_kernel<<<(NBOND * NLAY * 16 * 128 + 255) / 256, 256, 0, stream>>>(msgW, WpM);
    pack_gru_kernel<<<(2 * NTYPE * 2 * 16 * 384 + 255) / 256, 256, 0, stream>>>(Wih, Whh, WpG);

    for (int pass = 0; pass < 3; ++pass) {
        (void)hipMemsetAsync(m_non, 0, (size_t)NNODES * 128 * 4, stream);
        mlp_agg_mfma<<<dim3(NBOND, 128), 512, 0, stream>>>(hT, WpM, g, m_non, m_uni);
        gru_mfma<<<dim3(NNODES / 64, NTYPE, 2), 256, 0, stream>>>(hT, m_non, m_uni, counts, bucket,
                                                                  WpG, bih, bhh);
    }
}